// Round 1
// 168.949 us; speedup vs baseline: 1.0763x; 1.0763x over previous
//
#include <hip/hip_runtime.h>
#include <hip/hip_bf16.h>
#include <cstdint>
#include <cstddef>

// ---------------------------------------------------------------------------
// MAT_31997506355868 round 10.
// R9 + (a) XCD head-grouping swizzle: all 8 row/col-blocks of head h placed
// at blockIdx ≡ h (mod 8) so each XCD's L2 holds 8 heads' K/V (2 MB, L2-fit);
// qkv gets an (8m x 4n)-per-XCD grouping (A panel L2-resident, shared over z).
// (b) attn/colsum chunk loops rebuilt as 3-buffer counted-vmcnt pipelines
// (m201 idiom): raw s_barrier + s_waitcnt vmcnt(N), stage issued 2 chunks
// ahead -> no vmcnt(0) drain of the in-flight prefetch at each barrier.
// ---------------------------------------------------------------------------

typedef short short8 __attribute__((ext_vector_type(8)));
typedef short short4v __attribute__((ext_vector_type(4)));
typedef float f32x4 __attribute__((ext_vector_type(4)));

#define MFMA32(a, b, c) __builtin_amdgcn_mfma_f32_16x16x32_bf16(a, b, c, 0, 0, 0)
#define MFMA16x16(a, b, c) __builtin_amdgcn_mfma_f32_16x16x16bf16_1k(a, b, c, 0, 0, 0)
#define ATT_SCALE 0.03125f

__device__ __forceinline__ short f2bf(float f) {
  union { float f; uint32_t u; } x; x.f = f;
  uint32_t u = x.u + 0x7fffu + ((x.u >> 16) & 1u);  // RNE
  return (short)(u >> 16);
}

// pack two fp32 -> two bf16 (truncate) in one v_perm_b32
__device__ __forceinline__ uint32_t pk_bf16_trunc(float lo, float hi) {
  return __builtin_amdgcn_perm(__float_as_uint(hi), __float_as_uint(lo),
                               0x07060302u);
}

// async global->LDS; LDS dest = wave-uniform base + lane*size
#define GLDS16(gp, lp)                                                        \
  __builtin_amdgcn_global_load_lds(                                           \
      (const __attribute__((address_space(1))) void*)(gp),                    \
      (__attribute__((address_space(3))) void*)(lp), 16, 0, 0)
#define GLDS4(gp, lp)                                                         \
  __builtin_amdgcn_global_load_lds(                                           \
      (const __attribute__((address_space(1))) void*)(gp),                    \
      (__attribute__((address_space(3))) void*)(lp), 4, 0, 0)

// ---- fp32 -> bf16 convert -------------------------------------------------
__global__ __launch_bounds__(256) void convert_kernel(
    const float* __restrict__ x, const float* __restrict__ wq,
    const float* __restrict__ wk, const float* __restrict__ wv,
    short* __restrict__ xb, short* __restrict__ wb) {
  const long XN = 4L * 1024 * 1024, WN = 1024L * 1024;
  long e = (long)(blockIdx.x * blockDim.x + threadIdx.x) * 4;
  const float* src; short* dst;
  if (e < XN)               { src = x  + e;                dst = xb + e; }
  else if (e < XN + WN)     { src = wq + (e - XN);         dst = wb + (e - XN); }
  else if (e < XN + 2 * WN) { src = wk + (e - XN - WN);    dst = wb + (e - XN); }
  else                      { src = wv + (e - XN - 2*WN);  dst = wb + (e - XN); }
  f32x4 v = *(const f32x4*)src;
  short4v o;
  o[0] = f2bf(v[0]); o[1] = f2bf(v[1]); o[2] = f2bf(v[2]); o[3] = f2bf(v[3]);
  *(short4v*)dst = o;
}

// ---- QKV projection (m97 structure, BK=32).  Q pre-scaled by 1/32. --------
// z==2 (V): epilogue writes V^T frag-major (vtp) directly.
// XCD swizzle: XCD r owns an 8-m-block x 4-n-block patch (A 2 MB shared over
// z + B 1 MB/z) instead of streaming all of A per XCD.
__global__ __launch_bounds__(256, 3) void qkv_gemm(
    const short* __restrict__ xb, const short* __restrict__ wb,
    const float* __restrict__ bq, const float* __restrict__ bk,
    const float* __restrict__ bv, short* __restrict__ qb,
    short* __restrict__ kb, short* __restrict__ vtp) {
  __shared__ short As[128 * 32];
  __shared__ short Bs[128 * 32];
  const int tid = threadIdx.x;
  const int lane = tid & 63;
  const int lm = lane & 15, quad = lane >> 4;
  const int wave = tid >> 6, wy = wave >> 1, wx = wave & 1;
  // flat = bx + 8*by; XCD = flat & 7 (round-robin assumption, m157)
  const int f = blockIdx.x + (blockIdx.y << 3);
  const int r8 = f & 7, s = f >> 3;                 // r8 = XCD, s in [0,32)
  const int m0 = (((r8 >> 1) << 3) + (s & 7)) * 128;  // my in [0,32)
  const int n0 = (((r8 & 1) << 2) + (s >> 3)) * 128;  // nx in [0,8)
  const int z = blockIdx.z;
  const short* w = wb + (size_t)z * (1024 * 1024);
  const float* bias = (z == 0) ? bq : (z == 1) ? bk : bv;
  const float scl = (z == 0) ? ATT_SCALE : 1.0f;

  const short* gA0 = xb + (size_t)(m0 + (tid >> 2)) * 1024 + (tid & 3) * 8;
  const short* gA1 = gA0 + 64 * 1024;
  const short* gB0 = w  + (size_t)(n0 + (tid >> 2)) * 1024 + (tid & 3) * 8;
  const short* gB1 = gB0 + 64 * 1024;
  short* lA0 = As + tid * 8;
  short* lA1 = As + (tid + 256) * 8;
  short* lB0 = Bs + tid * 8;
  short* lB1 = Bs + (tid + 256) * 8;

  f32x4 acc[4][4];
#pragma unroll
  for (int i = 0; i < 4; i++)
#pragma unroll
    for (int j = 0; j < 4; j++) acc[i][j] = (f32x4){0.f, 0.f, 0.f, 0.f};

  for (int k0 = 0; k0 < 1024; k0 += 32) {
    GLDS16(gA0 + k0, lA0);
    GLDS16(gA1 + k0, lA1);
    GLDS16(gB0 + k0, lB0);
    GLDS16(gB1 + k0, lB1);
    __syncthreads();
    short8 a[4], b[4];
#pragma unroll
    for (int t = 0; t < 4; t++)
      a[t] = *(const short8*)(As + (wy * 64 + t * 16 + lm) * 32 + quad * 8);
#pragma unroll
    for (int t = 0; t < 4; t++)
      b[t] = *(const short8*)(Bs + (wx * 64 + t * 16 + lm) * 32 + quad * 8);
#pragma unroll
    for (int mt = 0; mt < 4; mt++)
#pragma unroll
      for (int nt = 0; nt < 4; nt++)
        acc[mt][nt] = MFMA32(a[mt], b[nt], acc[mt][nt]);
    __syncthreads();
  }
  if (z == 2) {
    // V: write transposed frag-major directly
#pragma unroll
    for (int nt = 0; nt < 4; nt++) {
      const int n = n0 + wx * 64 + nt * 16 + lm;
      const float bn = bias[n];
      const size_t nbase = (size_t)((n >> 4) & 3) * 16384 +
                           (size_t)((((n >> 8) & 3) * 16 + (n & 15)) * 4 +
                                    ((n >> 6) & 3));
#pragma unroll
      for (int mt = 0; mt < 4; mt++) {
#pragma unroll
        for (int r = 0; r < 4; r++) {
          const int m = m0 + wy * 64 + mt * 16 + quad * 4 + r;
          vtp[(size_t)(m >> 6) * 65536 + nbase + (size_t)(m & 63) * 256] =
              f2bf(acc[mt][nt][r] + bn);
        }
      }
    }
  } else {
    short* out = (z == 0) ? qb : kb;
#pragma unroll
    for (int nt = 0; nt < 4; nt++) {
      const int n = n0 + wx * 64 + nt * 16 + lm;
      const float bn = bias[n];
#pragma unroll
      for (int mt = 0; mt < 4; mt++) {
        const int mb = m0 + wy * 64 + mt * 16 + quad * 4;
#pragma unroll
        for (int r = 0; r < 4; r++)
          out[(size_t)(mb + r) * 1024 + n] = f2bf((acc[mt][nt][r] + bn) * scl);
      }
    }
  }
}

// ---- FLASH attention: 2 i-tiles/wave, 64-j chunks, 3-buf K/V pipeline -----
// grid 512 = 64 heads x 8 blocks; XCD swizzle groups all 8 blocks of a head
// on one XCD (K/V L2-resident).  Stage issued 2 chunks ahead; per-chunk
// barrier waits vmcnt(4) (own newest stage stays in flight), never 0.
__global__ __launch_bounds__(256, 2) void attn_kernel(
    const short* __restrict__ qb, const short* __restrict__ kb,
    const short* __restrict__ vtp, const float* __restrict__ x,
    const float* __restrict__ gamma, const float* __restrict__ beta,
    float* __restrict__ out1, float* __restrict__ rvW) {
  __shared__ short Ks[3][64 * 64];      // 3 x 8 KB
  __shared__ short Vs[3][4 * 4 * 256];  // 3 x 8 KB

  const int tid = threadIdx.x;
  const int lane = tid & 63, wave = tid >> 6;
  const int lm = lane & 15, quad = lane >> 4;
  // XCD swizzle: bid ≡ h (mod 8)  ->  head's 8 blocks share one XCD's L2
  const int bid = blockIdx.x;
  const int h = ((bid >> 6) << 3) + (bid & 7);
  const int bb = (bid >> 3) & 7;
  const short* Qh = qb + (size_t)h * 65536;
  const short* Kh = kb + (size_t)h * 65536;
  const short* Vp = vtp + (size_t)h * 65536;
  const int i0 = bb * 128 + wave * 32;   // tiles at i0 and i0+16

  const short8 qA0 = *(const short8*)(Qh + (size_t)(i0 + lm) * 64 + quad * 8);
  const short8 qA1 = *(const short8*)(Qh + (size_t)(i0 + lm) * 64 + 32 + quad * 8);
  const short8 qB0 = *(const short8*)(Qh + (size_t)(i0 + 16 + lm) * 64 + quad * 8);
  const short8 qB1 = *(const short8*)(Qh + (size_t)(i0 + 16 + lm) * 64 + 32 + quad * 8);

  // staging pointers (chunk-invariant parts)
  const int c0 = tid, c1 = tid + 256;
  const short* gK0 = Kh + (size_t)(c0 >> 3) * 64 + ((c0 & 7) ^ ((c0 >> 3) & 7)) * 8;
  const short* gK1 = Kh + (size_t)(c1 >> 3) * 64 + ((c1 & 7) ^ ((c1 >> 3) & 7)) * 8;
  const short* gV0 = Vp + (c0 >> 7) * 16384 + ((c0 >> 5) & 3) * 256 + (c0 & 31) * 8;
  const short* gV1 = Vp + (c1 >> 7) * 16384 + ((c1 >> 5) & 3) * 256 + (c1 & 31) * 8;
  const int lK0 = c0 * 8, lK1 = c1 * 8;

#define ATTN_STAGE(c, buf)                                                    \
  do {                                                                        \
    const int ko_ = ((c) & 15) * 4096, vo_ = ((c) & 15) * 1024;               \
    GLDS16(gK0 + ko_, &Ks[buf][0] + lK0);                                     \
    GLDS16(gK1 + ko_, &Ks[buf][0] + lK1);                                     \
    GLDS16(gV0 + vo_, &Vs[buf][0] + lK0);                                     \
    GLDS16(gV1 + vo_, &Vs[buf][0] + lK1);                                     \
  } while (0)

  f32x4 accA[4], accB[4];
#pragma unroll
  for (int t = 0; t < 4; t++) {
    accA[t] = (f32x4){0.f, 0.f, 0.f, 0.f};
    accB[t] = (f32x4){0.f, 0.f, 0.f, 0.f};
  }
  float dsA[4] = {0.f, 0.f, 0.f, 0.f};
  float dsB[4] = {0.f, 0.f, 0.f, 0.f};

  const int swz0 = (quad ^ (lm & 7)) * 8;
  const int swz1 = ((quad + 4) ^ (lm & 7)) * 8;

  // prologue: chunks 0,1 in flight
  ATTN_STAGE(0, 0);
  ATTN_STAGE(1, 1);

  for (int ch = 0; ch < 16; ch++) {
    const int b = ch % 3, bs = (ch + 2) % 3;
    // own stage(ch) landed (4 newest = stage(ch+1) stay in flight); then
    // barrier publishes every wave's slice of buf b.
    asm volatile("s_waitcnt vmcnt(4)" ::: "memory");
    __builtin_amdgcn_s_barrier();
#pragma unroll
    for (int jj = 0; jj < 4; jj++) {
      const short* krow = &Ks[b][(jj * 16 + lm) * 64];
      const short8 kf0 = *(const short8*)(krow + swz0);
      const short8 kf1 = *(const short8*)(krow + swz1);
      f32x4 zA = {0.f, 0.f, 0.f, 0.f};
      zA = MFMA32(kf0, qA0, zA);
      zA = MFMA32(kf1, qA1, zA);
      f32x4 zB = {0.f, 0.f, 0.f, 0.f};
      zB = MFMA32(kf0, qB0, zB);
      zB = MFMA32(kf1, qB1, zB);
      float pA[4], pB[4];
#pragma unroll
      for (int r = 0; r < 4; r++) {
        pA[r] = __expf(fmaxf(zA[r], 0.f));   // unnormalized
        dsA[r] += pA[r];
        pB[r] = __expf(fmaxf(zB[r], 0.f));
        dsB[r] += pB[r];
      }
      union { uint32_t u[2]; short4v s; } puA, puB;
      puA.u[0] = pk_bf16_trunc(pA[0], pA[1]);
      puA.u[1] = pk_bf16_trunc(pA[2], pA[3]);
      puB.u[0] = pk_bf16_trunc(pB[0], pB[1]);
      puB.u[1] = pk_bf16_trunc(pB[2], pB[3]);
      const short* vbase = &Vs[b][jj * 256 + lane * 4];
#pragma unroll
      for (int dt = 0; dt < 4; dt++) {
        const short4v vtf = *(const short4v*)(vbase + dt * 1024);
        accA[dt] = MFMA16x16(vtf, puA.s, accA[dt]);
        accB[dt] = MFMA16x16(vtf, puB.s, accB[dt]);
      }
    }
    // issue stage(ch+2) into the buffer compute(ch-1) just vacated; ch==14
    // issues a dummy (chunk 0) so the vmcnt(4) immediate stays uniform.
    if (ch < 15) ATTN_STAGE(ch + 2, bs);
  }
  asm volatile("s_waitcnt vmcnt(0)" ::: "memory");  // drain dummy before exit

  float tA = (dsA[0] + dsA[1]) + (dsA[2] + dsA[3]);
  tA += __shfl_xor(tA, 16);
  tA += __shfl_xor(tA, 32);
  float tB = (dsB[0] + dsB[1]) + (dsB[2] + dsB[3]);
  tB += __shfl_xor(tB, 16);
  tB += __shfl_xor(tB, 32);
  const float rvA = 1.f / tA;
  const float rvB = 1.f / tB;
  if (lane < 16) {
    rvW[h * 1024 + i0 + lm] = rvA;
    rvW[h * 1024 + i0 + 16 + lm] = rvB;
  }

  // ---- LN epilogue (R4-verified 2-tile): n = lm*64 + dt*16 + quad*4+r -----
  const int mA = h * 64 + bb * 8 + wave * 2;  // tile A row; tile B = mA+1
  const int nb = lm * 64 + quad * 4;
#pragma unroll
  for (int tile = 0; tile < 2; tile++) {
    const int m = mA + tile;
    const f32x4* accT = tile ? accB : accA;
    const float rv = tile ? rvB : rvA;
    const float* xr = x + (size_t)m * 1024;
    float hv[4][4], s1 = 0.f, s2 = 0.f;
#pragma unroll
    for (int dt = 0; dt < 4; dt++) {
      f32x4 xv = *(const f32x4*)(xr + nb + dt * 16);
#pragma unroll
      for (int r = 0; r < 4; r++) {
        const float v = xv[r] + accT[dt][r] * rv;
        hv[dt][r] = v; s1 += v; s2 += v * v;
      }
    }
#pragma unroll
    for (int mk = 1; mk < 64; mk <<= 1) {
      s1 += __shfl_xor(s1, mk);
      s2 += __shfl_xor(s2, mk);
    }
    const float mu = s1 * (1.f / 1024.f);
    const float var = s2 * (1.f / 1024.f) - mu * mu;
    const float rstd = rsqrtf(var + 1e-5f);
    float* orow = out1 + (size_t)m * 1024;
#pragma unroll
    for (int dt = 0; dt < 4; dt++) {
      f32x4 gv = *(const f32x4*)(gamma + nb + dt * 16);
      f32x4 bv2 = *(const f32x4*)(beta + nb + dt * 16);
      f32x4 ov;
#pragma unroll
      for (int r = 0; r < 4; r++)
        ov[r] = (hv[dt][r] - mu) * rstd * gv[r] + bv2[r];
      *(f32x4*)(orow + nb + dt * 16) = ov;
    }
  }
}

// ---- colsum: 2 j-tiles/wave, 64-i chunks, 3-buf Q+rv pipeline -------------
// out2[h][j] = sum_i exp(relu(z_ij)) * rv_i.  XCD swizzle groups a head's 8
// j-blocks per XCD (Q_h L2-resident).  All waves stage rv (identical
// redundant writes, benign) so the per-wave vmcnt count is uniform (3).
__global__ __launch_bounds__(256, 2) void colsum_kernel(
    const short* __restrict__ qb, const short* __restrict__ kb,
    const float* __restrict__ rvW, float* __restrict__ out2) {
  __shared__ short Qs[3][64 * 64];  // 3 x 8 KB
  __shared__ float rvS[3][64];

  const int tid = threadIdx.x;
  const int lane = tid & 63, wave = tid >> 6;
  const int lm = lane & 15, quad = lane >> 4;
  const int bid = blockIdx.x;
  const int h = ((bid >> 6) << 3) + (bid & 7);
  const int jb = (bid >> 3) & 7;
  const int j0 = jb * 128 + wave * 32;   // tiles at j0 and j0+16
  const short* Qh = qb + (size_t)h * 65536;
  const short* Kh = kb + (size_t)h * 65536;
  const float* rvh = rvW + h * 1024;

  const short* krA = Kh + (size_t)(j0 + lm) * 64 + quad * 8;
  const short8 kA0 = *(const short8*)krA;
  const short8 kA1 = *(const short8*)(krA + 32);
  const short* krB = Kh + (size_t)(j0 + 16 + lm) * 64 + quad * 8;
  const short8 kB0 = *(const short8*)krB;
  const short8 kB1 = *(const short8*)(krB + 32);

  const int c0 = tid, c1 = tid + 256;
  const short* gQ0 = Qh + (size_t)(c0 >> 3) * 64 + ((c0 & 7) ^ ((c0 >> 3) & 7)) * 8;
  const short* gQ1 = Qh + (size_t)(c1 >> 3) * 64 + ((c1 & 7) ^ ((c1 >> 3) & 7)) * 8;
  const int lQ0 = c0 * 8, lQ1 = c1 * 8;

#define CS_STAGE(c, buf)                                                      \
  do {                                                                        \
    const int qo_ = ((c) & 15) * 4096;                                        \
    GLDS16(gQ0 + qo_, &Qs[buf][0] + lQ0);                                     \
    GLDS16(gQ1 + qo_, &Qs[buf][0] + lQ1);                                     \
    GLDS4(rvh + ((c) & 15) * 64 + lane, &rvS[buf][0]);                        \
  } while (0)

  const int swz0 = (quad ^ (lm & 7)) * 8;
  const int swz1 = ((quad + 4) ^ (lm & 7)) * 8;

  f32x4 csA = {0.f, 0.f, 0.f, 0.f};
  f32x4 csB = {0.f, 0.f, 0.f, 0.f};

  CS_STAGE(0, 0);
  CS_STAGE(1, 1);

  for (int ch = 0; ch < 16; ch++) {
    const int b = ch % 3, bs = (ch + 2) % 3;
    asm volatile("s_waitcnt vmcnt(3)" ::: "memory");
    __builtin_amdgcn_s_barrier();
#pragma unroll
    for (int ii = 0; ii < 4; ii++) {
      const short* qrow = &Qs[b][(ii * 16 + lm) * 64];
      const short8 qf0 = *(const short8*)(qrow + swz0);
      const short8 qf1 = *(const short8*)(qrow + swz1);
      f32x4 zA = {0.f, 0.f, 0.f, 0.f};
      zA = MFMA32(kA0, qf0, zA);
      zA = MFMA32(kA1, qf1, zA);
      f32x4 zB = {0.f, 0.f, 0.f, 0.f};
      zB = MFMA32(kB0, qf0, zB);
      zB = MFMA32(kB1, qf1, zB);
      const float rvv = rvS[b][ii * 16 + lm];
#pragma unroll
      for (int r = 0; r < 4; r++) {
        csA[r] += __expf(fmaxf(zA[r], 0.f)) * rvv;
        csB[r] += __expf(fmaxf(zB[r], 0.f)) * rvv;
      }
    }
    if (ch < 15) CS_STAGE(ch + 2, bs);
  }
  asm volatile("s_waitcnt vmcnt(0)" ::: "memory");

  // reduce over the 16 i-lanes within each quad
#pragma unroll
  for (int mk = 1; mk < 16; mk <<= 1)
#pragma unroll
    for (int r = 0; r < 4; r++) {
      csA[r] += __shfl_xor(csA[r], mk);
      csB[r] += __shfl_xor(csB[r], mk);
    }
  if (lm == 0) {
    *(f32x4*)(out2 + h * 1024 + j0 + quad * 4) = csA;
    *(f32x4*)(out2 + h * 1024 + j0 + 16 + quad * 4) = csB;
  }
}

extern "C" void kernel_launch(void* const* d_in, const int* in_sizes, int n_in,
                              void* d_out, int out_size, void* d_ws, size_t ws_size,
                              hipStream_t stream) {
  const float* x  = (const float*)d_in[0];
  const float* Wq = (const float*)d_in[1];
  const float* bq = (const float*)d_in[2];
  const float* Wk = (const float*)d_in[3];
  const float* bk = (const float*)d_in[4];
  const float* Wv = (const float*)d_in[5];
  const float* bv = (const float*)d_in[6];
  const float* gamma = (const float*)d_in[7];
  const float* beta  = (const float*)d_in[8];

  float* out1 = (float*)d_out;                       // 4*1024*1024
  float* out2 = out1 + 4L * 1024 * 1024;             // 64*1024 colsums

  short* xb = (short*)d_ws;                          // 4096x1024 bf16
  short* wb = xb + 4L * 1024 * 1024;                 // 3x 1024x1024 bf16
  short* qb = wb + 3L * 1024 * 1024;
  short* kb = qb + 4L * 1024 * 1024;
  short* vtp = kb + 4L * 1024 * 1024;                // V^T frag-major
  float* rvW = (float*)wb;                           // reuse wb after qkv_gemm

  convert_kernel<<<7168, 256, 0, stream>>>(x, Wq, Wk, Wv, xb, wb);
  qkv_gemm<<<dim3(8, 32, 3), 256, 0, stream>>>(xb, wb, bq, bk, bv, qb, kb, vtp);
  attn_kernel<<<512, 256, 0, stream>>>(qb, kb, vtp, x, gamma, beta, out1, rvW);
  colsum_kernel<<<512, 256, 0, stream>>>(qb, kb, rvW, out2);
}

// Round 2
// 165.272 us; speedup vs baseline: 1.1002x; 1.0222x over previous
//
#include <hip/hip_runtime.h>
#include <hip/hip_bf16.h>
#include <cstdint>
#include <cstddef>

// ---------------------------------------------------------------------------
// MAT_31997506355868 round 11.
// R10 + (a) qkv_gemm rebuilt as m97 BK=64 (half the barriers) with
// both-sides XOR chunk swizzle (pre-swizzled global source, linear GLDS dest,
// swizzled ds_read) -> conflict-minimal ds_read_b128.
// (b) colsum split by i-halves: grid 1024, 8 chunks/block, 4 blocks/CU
// (launch_bounds(256,4)) + atomicAdd merge; out2 zeroed by convert_kernel.
// (c) T5 s_setprio(1/0) around the compute phase in attn+colsum (phase-split
// counted-vmcnt schedule exists -> T5 mechanism applies, m218b/m191).
// ---------------------------------------------------------------------------

typedef short short8 __attribute__((ext_vector_type(8)));
typedef short short4v __attribute__((ext_vector_type(4)));
typedef float f32x4 __attribute__((ext_vector_type(4)));

#define MFMA32(a, b, c) __builtin_amdgcn_mfma_f32_16x16x32_bf16(a, b, c, 0, 0, 0)
#define MFMA16x16(a, b, c) __builtin_amdgcn_mfma_f32_16x16x16bf16_1k(a, b, c, 0, 0, 0)
#define ATT_SCALE 0.03125f

__device__ __forceinline__ short f2bf(float f) {
  union { float f; uint32_t u; } x; x.f = f;
  uint32_t u = x.u + 0x7fffu + ((x.u >> 16) & 1u);  // RNE
  return (short)(u >> 16);
}

// pack two fp32 -> two bf16 (truncate) in one v_perm_b32
__device__ __forceinline__ uint32_t pk_bf16_trunc(float lo, float hi) {
  return __builtin_amdgcn_perm(__float_as_uint(hi), __float_as_uint(lo),
                               0x07060302u);
}

// async global->LDS; LDS dest = wave-uniform base + lane*size
#define GLDS16(gp, lp)                                                        \
  __builtin_amdgcn_global_load_lds(                                           \
      (const __attribute__((address_space(1))) void*)(gp),                    \
      (__attribute__((address_space(3))) void*)(lp), 16, 0, 0)
#define GLDS4(gp, lp)                                                         \
  __builtin_amdgcn_global_load_lds(                                           \
      (const __attribute__((address_space(1))) void*)(gp),                    \
      (__attribute__((address_space(3))) void*)(lp), 4, 0, 0)

// ---- fp32 -> bf16 convert + zero out2 -------------------------------------
__global__ __launch_bounds__(256) void convert_kernel(
    const float* __restrict__ x, const float* __restrict__ wq,
    const float* __restrict__ wk, const float* __restrict__ wv,
    short* __restrict__ xb, short* __restrict__ wb,
    float* __restrict__ out2) {
  if (blockIdx.x >= 7168) {  // zero out2 (64K floats) for colsum atomics
    const int idx = (blockIdx.x - 7168) * 256 + threadIdx.x;
    *(f32x4*)(out2 + (size_t)idx * 4) = (f32x4){0.f, 0.f, 0.f, 0.f};
    return;
  }
  const long XN = 4L * 1024 * 1024, WN = 1024L * 1024;
  long e = (long)(blockIdx.x * blockDim.x + threadIdx.x) * 4;
  const float* src; short* dst;
  if (e < XN)               { src = x  + e;                dst = xb + e; }
  else if (e < XN + WN)     { src = wq + (e - XN);         dst = wb + (e - XN); }
  else if (e < XN + 2 * WN) { src = wk + (e - XN - WN);    dst = wb + (e - XN); }
  else                      { src = wv + (e - XN - 2*WN);  dst = wb + (e - XN); }
  f32x4 v = *(const f32x4*)src;
  short4v o;
  o[0] = f2bf(v[0]); o[1] = f2bf(v[1]); o[2] = f2bf(v[2]); o[3] = f2bf(v[3]);
  *(short4v*)dst = o;
}

// ---- QKV projection: m97 BK=64 + both-sides XOR swizzle.  Q scaled 1/32. --
// LDS[row][pos] holds global chunk pos^(row&7); read pos = (ks*4+quad)^(lm&7).
// z==2 (V): epilogue writes V^T frag-major (vtp) directly.
__global__ __launch_bounds__(256, 3) void qkv_gemm(
    const short* __restrict__ xb, const short* __restrict__ wb,
    const float* __restrict__ bq, const float* __restrict__ bk,
    const float* __restrict__ bv, short* __restrict__ qb,
    short* __restrict__ kb, short* __restrict__ vtp) {
  __shared__ short As[128 * 64];   // 16 KB
  __shared__ short Bs[128 * 64];   // 16 KB
  const int tid = threadIdx.x;
  const int lane = tid & 63;
  const int lm = lane & 15, quad = lane >> 4;
  const int wave = tid >> 6, wy = wave >> 1, wx = wave & 1;
  // flat = bx + 8*by; XCD = flat & 7 (x-fastest round-robin)
  const int f = blockIdx.x + (blockIdx.y << 3);
  const int r8 = f & 7, s = f >> 3;
  const int m0 = (((r8 >> 1) << 3) + (s & 7)) * 128;
  const int n0 = (((r8 & 1) << 2) + (s >> 3)) * 128;
  const int z = blockIdx.z;
  const short* w = wb + (size_t)z * (1024 * 1024);
  const float* bias = (z == 0) ? bq : (z == 1) ? bk : bv;
  const float scl = (z == 0) ? ATT_SCALE : 1.0f;

  // staging: thread t loads row (t>>3)+32q, source chunk (t&7)^(row&7);
  // GLDS dest linear (row-major [128][64]); (row&7) invariant in q.
  const int srow = tid >> 3;
  const int schk = (tid & 7) ^ (srow & 7);
  const short* gA = xb + (size_t)(m0 + srow) * 1024 + schk * 8;
  const short* gB = w  + (size_t)(n0 + srow) * 1024 + schk * 8;
  short* lA = As + tid * 8;
  short* lB = Bs + tid * 8;

  f32x4 acc[4][4];
#pragma unroll
  for (int i = 0; i < 4; i++)
#pragma unroll
    for (int j = 0; j < 4; j++) acc[i][j] = (f32x4){0.f, 0.f, 0.f, 0.f};

  for (int k0 = 0; k0 < 1024; k0 += 64) {
#pragma unroll
    for (int q = 0; q < 4; q++) {
      GLDS16(gA + k0 + q * 32 * 1024, lA + q * 2048);
      GLDS16(gB + k0 + q * 32 * 1024, lB + q * 2048);
    }
    __syncthreads();
#pragma unroll
    for (int ks = 0; ks < 2; ks++) {
      const int ck = (((ks << 2) + quad) ^ (lm & 7)) * 8;  // swizzled chunk
      short8 a[4], b[4];
#pragma unroll
      for (int t = 0; t < 4; t++) {
        a[t] = *(const short8*)(As + (wy * 64 + t * 16 + lm) * 64 + ck);
        b[t] = *(const short8*)(Bs + (wx * 64 + t * 16 + lm) * 64 + ck);
      }
#pragma unroll
      for (int mt = 0; mt < 4; mt++)
#pragma unroll
        for (int nt = 0; nt < 4; nt++)
          acc[mt][nt] = MFMA32(a[mt], b[nt], acc[mt][nt]);
    }
    __syncthreads();
  }
  if (z == 2) {
    // V: write transposed frag-major directly
#pragma unroll
    for (int nt = 0; nt < 4; nt++) {
      const int n = n0 + wx * 64 + nt * 16 + lm;
      const float bn = bias[n];
      const size_t nbase = (size_t)((n >> 4) & 3) * 16384 +
                           (size_t)((((n >> 8) & 3) * 16 + (n & 15)) * 4 +
                                    ((n >> 6) & 3));
#pragma unroll
      for (int mt = 0; mt < 4; mt++) {
#pragma unroll
        for (int r = 0; r < 4; r++) {
          const int m = m0 + wy * 64 + mt * 16 + quad * 4 + r;
          vtp[(size_t)(m >> 6) * 65536 + nbase + (size_t)(m & 63) * 256] =
              f2bf(acc[mt][nt][r] + bn);
        }
      }
    }
  } else {
    short* out = (z == 0) ? qb : kb;
#pragma unroll
    for (int nt = 0; nt < 4; nt++) {
      const int n = n0 + wx * 64 + nt * 16 + lm;
      const float bn = bias[n];
#pragma unroll
      for (int mt = 0; mt < 4; mt++) {
        const int mb = m0 + wy * 64 + mt * 16 + quad * 4;
#pragma unroll
        for (int r = 0; r < 4; r++)
          out[(size_t)(mb + r) * 1024 + n] = f2bf((acc[mt][nt][r] + bn) * scl);
      }
    }
  }
}

// ---- FLASH attention: 2 i-tiles/wave, 64-j chunks, 3-buf K/V pipeline -----
// grid 512 = 64 heads x 8 blocks; head-grouped XCD swizzle.  Counted
// vmcnt(4): own stage(ch) landed, stage(ch+1) stays in flight.  T5 setprio
// around the compute phase.
__global__ __launch_bounds__(256, 2) void attn_kernel(
    const short* __restrict__ qb, const short* __restrict__ kb,
    const short* __restrict__ vtp, const float* __restrict__ x,
    const float* __restrict__ gamma, const float* __restrict__ beta,
    float* __restrict__ out1, float* __restrict__ rvW) {
  __shared__ short Ks[3][64 * 64];      // 3 x 8 KB
  __shared__ short Vs[3][4 * 4 * 256];  // 3 x 8 KB

  const int tid = threadIdx.x;
  const int lane = tid & 63, wave = tid >> 6;
  const int lm = lane & 15, quad = lane >> 4;
  const int bid = blockIdx.x;
  const int h = ((bid >> 6) << 3) + (bid & 7);
  const int bb = (bid >> 3) & 7;
  const short* Qh = qb + (size_t)h * 65536;
  const short* Kh = kb + (size_t)h * 65536;
  const short* Vp = vtp + (size_t)h * 65536;
  const int i0 = bb * 128 + wave * 32;   // tiles at i0 and i0+16

  const short8 qA0 = *(const short8*)(Qh + (size_t)(i0 + lm) * 64 + quad * 8);
  const short8 qA1 = *(const short8*)(Qh + (size_t)(i0 + lm) * 64 + 32 + quad * 8);
  const short8 qB0 = *(const short8*)(Qh + (size_t)(i0 + 16 + lm) * 64 + quad * 8);
  const short8 qB1 = *(const short8*)(Qh + (size_t)(i0 + 16 + lm) * 64 + 32 + quad * 8);

  const int c0 = tid, c1 = tid + 256;
  const short* gK0 = Kh + (size_t)(c0 >> 3) * 64 + ((c0 & 7) ^ ((c0 >> 3) & 7)) * 8;
  const short* gK1 = Kh + (size_t)(c1 >> 3) * 64 + ((c1 & 7) ^ ((c1 >> 3) & 7)) * 8;
  const short* gV0 = Vp + (c0 >> 7) * 16384 + ((c0 >> 5) & 3) * 256 + (c0 & 31) * 8;
  const short* gV1 = Vp + (c1 >> 7) * 16384 + ((c1 >> 5) & 3) * 256 + (c1 & 31) * 8;
  const int lK0 = c0 * 8, lK1 = c1 * 8;

#define ATTN_STAGE(c, buf)                                                    \
  do {                                                                        \
    const int ko_ = ((c) & 15) * 4096, vo_ = ((c) & 15) * 1024;               \
    GLDS16(gK0 + ko_, &Ks[buf][0] + lK0);                                     \
    GLDS16(gK1 + ko_, &Ks[buf][0] + lK1);                                     \
    GLDS16(gV0 + vo_, &Vs[buf][0] + lK0);                                     \
    GLDS16(gV1 + vo_, &Vs[buf][0] + lK1);                                     \
  } while (0)

  f32x4 accA[4], accB[4];
#pragma unroll
  for (int t = 0; t < 4; t++) {
    accA[t] = (f32x4){0.f, 0.f, 0.f, 0.f};
    accB[t] = (f32x4){0.f, 0.f, 0.f, 0.f};
  }
  float dsA[4] = {0.f, 0.f, 0.f, 0.f};
  float dsB[4] = {0.f, 0.f, 0.f, 0.f};

  const int swz0 = (quad ^ (lm & 7)) * 8;
  const int swz1 = ((quad + 4) ^ (lm & 7)) * 8;

  ATTN_STAGE(0, 0);
  ATTN_STAGE(1, 1);

  for (int ch = 0; ch < 16; ch++) {
    const int b = ch % 3, bs = (ch + 2) % 3;
    asm volatile("s_waitcnt vmcnt(4)" ::: "memory");
    __builtin_amdgcn_s_barrier();
    __builtin_amdgcn_s_setprio(1);
#pragma unroll
    for (int jj = 0; jj < 4; jj++) {
      const short* krow = &Ks[b][(jj * 16 + lm) * 64];
      const short8 kf0 = *(const short8*)(krow + swz0);
      const short8 kf1 = *(const short8*)(krow + swz1);
      f32x4 zA = {0.f, 0.f, 0.f, 0.f};
      zA = MFMA32(kf0, qA0, zA);
      zA = MFMA32(kf1, qA1, zA);
      f32x4 zB = {0.f, 0.f, 0.f, 0.f};
      zB = MFMA32(kf0, qB0, zB);
      zB = MFMA32(kf1, qB1, zB);
      float pA[4], pB[4];
#pragma unroll
      for (int r = 0; r < 4; r++) {
        pA[r] = __expf(fmaxf(zA[r], 0.f));   // unnormalized
        dsA[r] += pA[r];
        pB[r] = __expf(fmaxf(zB[r], 0.f));
        dsB[r] += pB[r];
      }
      union { uint32_t u[2]; short4v s; } puA, puB;
      puA.u[0] = pk_bf16_trunc(pA[0], pA[1]);
      puA.u[1] = pk_bf16_trunc(pA[2], pA[3]);
      puB.u[0] = pk_bf16_trunc(pB[0], pB[1]);
      puB.u[1] = pk_bf16_trunc(pB[2], pB[3]);
      const short* vbase = &Vs[b][jj * 256 + lane * 4];
#pragma unroll
      for (int dt = 0; dt < 4; dt++) {
        const short4v vtf = *(const short4v*)(vbase + dt * 1024);
        accA[dt] = MFMA16x16(vtf, puA.s, accA[dt]);
        accB[dt] = MFMA16x16(vtf, puB.s, accB[dt]);
      }
    }
    __builtin_amdgcn_s_setprio(0);
    // ch==14 issues a dummy (chunk 0) so the vmcnt(4) immediate stays uniform
    if (ch < 15) ATTN_STAGE(ch + 2, bs);
  }
  asm volatile("s_waitcnt vmcnt(0)" ::: "memory");

  float tA = (dsA[0] + dsA[1]) + (dsA[2] + dsA[3]);
  tA += __shfl_xor(tA, 16);
  tA += __shfl_xor(tA, 32);
  float tB = (dsB[0] + dsB[1]) + (dsB[2] + dsB[3]);
  tB += __shfl_xor(tB, 16);
  tB += __shfl_xor(tB, 32);
  const float rvA = 1.f / tA;
  const float rvB = 1.f / tB;
  if (lane < 16) {
    rvW[h * 1024 + i0 + lm] = rvA;
    rvW[h * 1024 + i0 + 16 + lm] = rvB;
  }

  // ---- LN epilogue (R4-verified 2-tile): n = lm*64 + dt*16 + quad*4+r -----
  const int mA = h * 64 + bb * 8 + wave * 2;  // tile A row; tile B = mA+1
  const int nb = lm * 64 + quad * 4;
#pragma unroll
  for (int tile = 0; tile < 2; tile++) {
    const int m = mA + tile;
    const f32x4* accT = tile ? accB : accA;
    const float rv = tile ? rvB : rvA;
    const float* xr = x + (size_t)m * 1024;
    float hv[4][4], s1 = 0.f, s2 = 0.f;
#pragma unroll
    for (int dt = 0; dt < 4; dt++) {
      f32x4 xv = *(const f32x4*)(xr + nb + dt * 16);
#pragma unroll
      for (int r = 0; r < 4; r++) {
        const float v = xv[r] + accT[dt][r] * rv;
        hv[dt][r] = v; s1 += v; s2 += v * v;
      }
    }
#pragma unroll
    for (int mk = 1; mk < 64; mk <<= 1) {
      s1 += __shfl_xor(s1, mk);
      s2 += __shfl_xor(s2, mk);
    }
    const float mu = s1 * (1.f / 1024.f);
    const float var = s2 * (1.f / 1024.f) - mu * mu;
    const float rstd = rsqrtf(var + 1e-5f);
    float* orow = out1 + (size_t)m * 1024;
#pragma unroll
    for (int dt = 0; dt < 4; dt++) {
      f32x4 gv = *(const f32x4*)(gamma + nb + dt * 16);
      f32x4 bv2 = *(const f32x4*)(beta + nb + dt * 16);
      f32x4 ov;
#pragma unroll
      for (int r = 0; r < 4; r++)
        ov[r] = (hv[dt][r] - mu) * rstd * gv[r] + bv2[r];
      *(f32x4*)(orow + nb + dt * 16) = ov;
    }
  }
}

// ---- colsum: 2 j-tiles/wave, i-SPLIT (half-range per block), 3-buf --------
// grid 1024 = 64 heads x 8 j-blocks x 2 i-halves; 8 chunks/block; 4 blocks/CU
// for latency hiding; atomicAdd merges the two i-halves into zeroed out2.
__global__ __launch_bounds__(256, 4) void colsum_kernel(
    const short* __restrict__ qb, const short* __restrict__ kb,
    const float* __restrict__ rvW, float* __restrict__ out2) {
  __shared__ short Qs[3][64 * 64];  // 3 x 8 KB
  __shared__ float rvS[3][64];

  const int tid = threadIdx.x;
  const int lane = tid & 63, wave = tid >> 6;
  const int lm = lane & 15, quad = lane >> 4;
  const int bid = blockIdx.x;                    // [hhh][i][jjj][lll]
  const int h = ((bid >> 7) << 3) + (bid & 7);   // bid ≡ h (mod 8)
  const int jb = (bid >> 3) & 7;
  const int ih = (bid >> 6) & 1;
  const int cb = ih * 8;                         // chunk base (i = cb*64)
  const int j0 = jb * 128 + wave * 32;
  const short* Qh = qb + (size_t)h * 65536;
  const short* Kh = kb + (size_t)h * 65536;
  const float* rvh = rvW + h * 1024;

  const short* krA = Kh + (size_t)(j0 + lm) * 64 + quad * 8;
  const short8 kA0 = *(const short8*)krA;
  const short8 kA1 = *(const short8*)(krA + 32);
  const short* krB = Kh + (size_t)(j0 + 16 + lm) * 64 + quad * 8;
  const short8 kB0 = *(const short8*)krB;
  const short8 kB1 = *(const short8*)(krB + 32);

  const int c0 = tid, c1 = tid + 256;
  const short* gQ0 = Qh + (size_t)(c0 >> 3) * 64 + ((c0 & 7) ^ ((c0 >> 3) & 7)) * 8;
  const short* gQ1 = Qh + (size_t)(c1 >> 3) * 64 + ((c1 & 7) ^ ((c1 >> 3) & 7)) * 8;
  const int lQ0 = c0 * 8, lQ1 = c1 * 8;

#define CS_STAGE(c, buf)                                                      \
  do {                                                                        \
    const int qo_ = ((c) & 15) * 4096;                                        \
    GLDS16(gQ0 + qo_, &Qs[buf][0] + lQ0);                                     \
    GLDS16(gQ1 + qo_, &Qs[buf][0] + lQ1);                                     \
    GLDS4(rvh + ((c) & 15) * 64 + lane, &rvS[buf][0]);                        \
  } while (0)

  const int swz0 = (quad ^ (lm & 7)) * 8;
  const int swz1 = ((quad + 4) ^ (lm & 7)) * 8;

  f32x4 csA = {0.f, 0.f, 0.f, 0.f};
  f32x4 csB = {0.f, 0.f, 0.f, 0.f};

  CS_STAGE(cb, 0);
  CS_STAGE(cb + 1, 1);

  for (int ch = 0; ch < 8; ch++) {
    const int b = ch % 3, bs = (ch + 2) % 3;
    asm volatile("s_waitcnt vmcnt(3)" ::: "memory");
    __builtin_amdgcn_s_barrier();
    __builtin_amdgcn_s_setprio(1);
#pragma unroll
    for (int ii = 0; ii < 4; ii++) {
      const short* qrow = &Qs[b][(ii * 16 + lm) * 64];
      const short8 qf0 = *(const short8*)(qrow + swz0);
      const short8 qf1 = *(const short8*)(qrow + swz1);
      f32x4 zA = {0.f, 0.f, 0.f, 0.f};
      zA = MFMA32(kA0, qf0, zA);
      zA = MFMA32(kA1, qf1, zA);
      f32x4 zB = {0.f, 0.f, 0.f, 0.f};
      zB = MFMA32(kB0, qf0, zB);
      zB = MFMA32(kB1, qf1, zB);
      const float rvv = rvS[b][ii * 16 + lm];
#pragma unroll
      for (int r = 0; r < 4; r++) {
        csA[r] += __expf(fmaxf(zA[r], 0.f)) * rvv;
        csB[r] += __expf(fmaxf(zB[r], 0.f)) * rvv;
      }
    }
    __builtin_amdgcn_s_setprio(0);
    // ch==6 issues a dummy so the vmcnt(3) immediate stays valid at ch==7
    if (ch < 7) CS_STAGE((cb + ch + 2) & 15, bs);
  }
  asm volatile("s_waitcnt vmcnt(0)" ::: "memory");

  // reduce over the 16 i-lanes within each quad, then merge i-halves
#pragma unroll
  for (int mk = 1; mk < 16; mk <<= 1)
#pragma unroll
    for (int r = 0; r < 4; r++) {
      csA[r] += __shfl_xor(csA[r], mk);
      csB[r] += __shfl_xor(csB[r], mk);
    }
  if (lm == 0) {
    float* pA = out2 + h * 1024 + j0 + quad * 4;
    float* pB = pA + 16;
#pragma unroll
    for (int r = 0; r < 4; r++) {
      atomicAdd(pA + r, csA[r]);
      atomicAdd(pB + r, csB[r]);
    }
  }
}

extern "C" void kernel_launch(void* const* d_in, const int* in_sizes, int n_in,
                              void* d_out, int out_size, void* d_ws, size_t ws_size,
                              hipStream_t stream) {
  const float* x  = (const float*)d_in[0];
  const float* Wq = (const float*)d_in[1];
  const float* bq = (const float*)d_in[2];
  const float* Wk = (const float*)d_in[3];
  const float* bk = (const float*)d_in[4];
  const float* Wv = (const float*)d_in[5];
  const float* bv = (const float*)d_in[6];
  const float* gamma = (const float*)d_in[7];
  const float* beta  = (const float*)d_in[8];

  float* out1 = (float*)d_out;                       // 4*1024*1024
  float* out2 = out1 + 4L * 1024 * 1024;             // 64*1024 colsums

  short* xb = (short*)d_ws;                          // 4096x1024 bf16
  short* wb = xb + 4L * 1024 * 1024;                 // 3x 1024x1024 bf16
  short* qb = wb + 3L * 1024 * 1024;
  short* kb = qb + 4L * 1024 * 1024;
  short* vtp = kb + 4L * 1024 * 1024;                // V^T frag-major
  float* rvW = (float*)wb;                           // reuse wb after qkv_gemm

  convert_kernel<<<7232, 256, 0, stream>>>(x, Wq, Wk, Wv, xb, wb, out2);
  qkv_gemm<<<dim3(8, 32, 3), 256, 0, stream>>>(xb, wb, bq, bk, bv, qb, kb, vtp);
  attn_kernel<<<512, 256, 0, stream>>>(qb, kb, vtp, x, gamma, beta, out1, rvW);
  colsum_kernel<<<1024, 256, 0, stream>>>(qb, kb, rvW, out2);
}